// Round 2
// baseline (639.474 us; speedup 1.0000x reference)
//
#include <hip/hip_runtime.h>
#include <hip/hip_bf16.h>
#include <cstdint>
#include <cstddef>

#define B_   64
#define S_   2048
#define INP_ 512
#define HID_ 512

typedef float          floatx4  __attribute__((ext_vector_type(4)));
typedef __bf16         bf16x8   __attribute__((ext_vector_type(8)));
typedef unsigned short ushortx8 __attribute__((ext_vector_type(8)));

__device__ __forceinline__ unsigned short f2bf(float f) {
  unsigned u = __float_as_uint(f);
  u += 0x7FFFu + ((u >> 16) & 1u);          // round-to-nearest-even
  return (unsigned short)(u >> 16);
}
// tanh(x) = 1 - 2/(exp(2x)+1); inf-safe.
__device__ __forceinline__ float fast_tanh(float x) {
  float u = __builtin_amdgcn_exp2f(x * 2.88539008177792681472f);
  return 1.0f - 2.0f * __builtin_amdgcn_rcpf(u + 1.0f);
}

// ---------------------------------------------------------------------------
// rowgemm: out[b,h] = bias[h] + dot(W[h,:], X[b,:])   (one wave per h)
// Used for hid = inp@Wl.T+bl  and  hidden = Wc@ctxbar+bc.
// ---------------------------------------------------------------------------
__global__ void rowgemm_kernel(const float* __restrict__ X, const float* __restrict__ W,
                               const float* __restrict__ bias, float* __restrict__ out)
{
  const int b = blockIdx.y;
  const int w = threadIdx.x >> 6, lane = threadIdx.x & 63;
  const int h = blockIdx.x * 4 + w;
  const float4* wr = (const float4*)(W + (size_t)h * 512) + lane * 2;
  const float4* xr = (const float4*)(X + (size_t)b * 512) + lane * 2;
  float4 w0 = wr[0], w1 = wr[1], x0 = xr[0], x1 = xr[1];
  float acc = w0.x*x0.x + w0.y*x0.y + w0.z*x0.z + w0.w*x0.w
            + w1.x*x1.x + w1.y*x1.y + w1.z*x1.z + w1.w*x1.w;
  #pragma unroll
  for (int off = 32; off; off >>= 1) acc += __shfl_xor(acc, off);
  if (lane == 0) out[b * 512 + h] = bias[h] + acc;
}

// ---------------------------------------------------------------------------
// pack Wc (fp32 [HID][INP]) -> bf16 in MFMA A-fragment lane order.
// pk[(m16*1024 + ks*64 + lane)*8 + j] = Wc[m16*16 + (lane&15)][ks*32 + (lane>>4)*8 + j]
// ---------------------------------------------------------------------------
__global__ void pack_wc_kernel(const float* __restrict__ Wc, unsigned short* __restrict__ pk)
{
  int g = blockIdx.x * 256 + threadIdx.x;       // 32768 threads
  int l = g & 63, ks = (g >> 6) & 15, m16 = g >> 10;
  int row = m16 * 16 + (l & 15);
  int kb  = ks * 32 + (l >> 4) * 8;
  const float4* s = (const float4*)(Wc + (size_t)row * 512 + kb);
  float4 a = s[0], c = s[1];
  ushortx8 o = { f2bf(a.x), f2bf(a.y), f2bf(a.z), f2bf(a.w),
                 f2bf(c.x), f2bf(c.y), f2bf(c.z), f2bf(c.w) };
  *(ushortx8*)(pk + (size_t)g * 8) = o;
}

// ---------------------------------------------------------------------------
// ctx_gemm: att[b,s] = sum_h V[h]*tanh(hid[b,h] + bc[h] + sum_k Wc[h,k]*context[b,s,k])
// Full-H (512) per block, 64-s tile, K staged 2x256 fp32 via async global_load_lds
// into a 64 KB LDS tile; bf16 conversion on the fragment-read path.
// Swizzle: LDS slot cl of row holds global 16B-chunk (cl ^ (row&7)).
// ---------------------------------------------------------------------------
__global__ __launch_bounds__(256, 2) void ctx_gemm_kernel(
    const float* __restrict__ context, const unsigned short* __restrict__ Wc_pk,
    const float* __restrict__ hid, const float* __restrict__ bc,
    const float* __restrict__ V, float* __restrict__ att)
{
  __shared__ alignas(16) float tile[64 * 256];    // 64 KB (reused as att_sm after K-loop)

  const int b    = blockIdx.y;
  const int s0   = blockIdx.x * 64;
  const int t    = threadIdx.x;
  const int lane = t & 63;
  const int w    = t >> 6;           // wave id: h-rows [w*128, w*128+128)
  const int quad = lane >> 4;
  const int l15  = lane & 15;

  floatx4 acc[8][4];
  #pragma unroll
  for (int m = 0; m < 8; ++m)
    #pragma unroll
    for (int n = 0; n < 4; ++n) { floatx4 z = {0.f,0.f,0.f,0.f}; acc[m][n] = z; }

  const unsigned short* apBase = Wc_pk + (size_t)(w * 8) * 8192 + lane * 8;
  const float* src = context + ((size_t)b * S_ + s0) * INP_;
  auto* ldsT = (__attribute__((address_space(3))) float*)tile;
  auto* gsrc = (const __attribute__((address_space(1))) float*)src;

  for (int stage = 0; stage < 2; ++stage) {
    __syncthreads();                               // previous compute done reading tile
    #pragma unroll
    for (int i = 0; i < 16; ++i) {
      int id  = t + i * 256;                       // 0..4095
      int row = id >> 6;                           // s-row 0..63
      int cl  = id & 63;                           // LDS chunk slot within row
      int cg  = cl ^ (row & 7);                    // global chunk it holds
      __builtin_amdgcn_global_load_lds(
          (const __attribute__((address_space(1))) void*)(gsrc + (size_t)row * INP_ + stage * 256 + cg * 4),
          (__attribute__((address_space(3))) void*)(ldsT + id * 4), 16, 0, 0);
    }
    __syncthreads();                               // vmcnt(0) drain + barrier
    #pragma unroll
    for (int ksl = 0; ksl < 8; ++ksl) {
      const int ksg = stage * 8 + ksl;
      bf16x8 af[8];
      #pragma unroll
      for (int m = 0; m < 8; ++m)
        af[m] = *(const bf16x8*)(apBase + (size_t)m * 8192 + ksg * 512);
      bf16x8 bfr[4];
      #pragma unroll
      for (int n = 0; n < 4; ++n) {
        const int row = n * 16 + l15;
        const int rw  = row & 7;
        const int c0  = ksl * 8 + quad * 2;        // even
        const float4* tp = (const float4*)tile + row * 64;
        float4 x0 = tp[c0 ^ rw];
        float4 x1 = tp[(c0 + 1) ^ rw];
        union { ushortx8 u; bf16x8 h; } cv;
        cv.u = (ushortx8){ f2bf(x0.x), f2bf(x0.y), f2bf(x0.z), f2bf(x0.w),
                           f2bf(x1.x), f2bf(x1.y), f2bf(x1.z), f2bf(x1.w) };
        bfr[n] = cv.h;
      }
      #pragma unroll
      for (int m = 0; m < 8; ++m)
        #pragma unroll
        for (int n = 0; n < 4; ++n)
          acc[m][n] = __builtin_amdgcn_mfma_f32_16x16x32_bf16(af[m], bfr[n], acc[m][n], 0, 0, 0);
    }
  }

  // Epilogue: att reduction over h.  C/D layout: col(s)=lane&15, row(h)=quad*4+reg.
  __syncthreads();                                 // tile dead, reuse as att accumulator
  if (t < 64) tile[t] = 0.0f;
  __syncthreads();

  float attacc[4] = {0.f, 0.f, 0.f, 0.f};
  #pragma unroll
  for (int m = 0; m < 8; ++m) {
    const int hb = w * 128 + m * 16 + quad * 4;
    #pragma unroll
    for (int r = 0; r < 4; ++r) {
      const int h = hb + r;
      const float bcv = bc[h], hv = hid[b * 512 + h], vv = V[h];
      #pragma unroll
      for (int n = 0; n < 4; ++n)
        attacc[n] += vv * fast_tanh(hv + bcv + acc[m][n][r]);
    }
  }
  #pragma unroll
  for (int n = 0; n < 4; ++n) {
    float v = attacc[n];
    v += __shfl_xor(v, 16);
    v += __shfl_xor(v, 32);
    if (lane < 16) atomicAdd(&tile[n * 16 + l15], v);
  }
  __syncthreads();
  if (t < 64) att[b * S_ + s0 + t] = tile[t];
}

// ---------------------------------------------------------------------------
// masked softmax over S per batch row (mask-encoding auto-detect, as before).
// ---------------------------------------------------------------------------
__global__ void softmax_kernel(const void* __restrict__ mask,
                               const float* __restrict__ att,
                               float* __restrict__ alpha)
{
  __shared__ int flags;
  __shared__ float red[8];
  const int b = blockIdx.x, t = threadIdx.x;
  const int lane = t & 63, w = t >> 6;
  if (t == 0) flags = 0;
  __syncthreads();
  int f = 0;
  const unsigned* mw = (const unsigned*)mask;
  for (int i = t; i < 512; i += 256) {
    unsigned v = mw[i];
    if (v > 1u) f |= 1;
    if (v != 0u && v != 0x3f800000u) f |= 2;
  }
  if (f) atomicOr(&flags, f);
  __syncthreads();
  const int fl = flags;
  const int mode = ((fl & 1) == 0) ? 0 : (((fl & 2) == 0) ? 1 : 2);

  float v[8]; bool msk[8];
  float vmax = -1e30f;
  #pragma unroll
  for (int i = 0; i < 8; ++i) {
    int idx = i * 256 + t;
    bool m;
    if (mode == 0)      m = ((const int*)mask)[b * S_ + idx] != 0;
    else if (mode == 1) m = ((const float*)mask)[b * S_ + idx] != 0.0f;
    else                m = ((const unsigned char*)mask)[b * S_ + idx] != 0;
    msk[i] = m;
    v[i] = att[b * S_ + idx];
    if (!m) vmax = fmaxf(vmax, v[i]);
  }
  #pragma unroll
  for (int off = 32; off; off >>= 1) vmax = fmaxf(vmax, __shfl_xor(vmax, off));
  if (lane == 0) red[w] = vmax;
  __syncthreads();
  vmax = fmaxf(fmaxf(red[0], red[1]), fmaxf(red[2], red[3]));

  float e[8], s = 0.0f;
  #pragma unroll
  for (int i = 0; i < 8; ++i) {
    e[i] = msk[i] ? 0.0f : __builtin_amdgcn_exp2f((v[i] - vmax) * 1.4426950408889634f);
    s += e[i];
  }
  #pragma unroll
  for (int off = 32; off; off >>= 1) s += __shfl_xor(s, off);
  if (lane == 0) red[4 + w] = s;
  __syncthreads();
  s = red[4] + red[5] + red[6] + red[7];
  float rinv = 1.0f / s;
  #pragma unroll
  for (int i = 0; i < 8; ++i)
    alpha[b * S_ + i * 256 + t] = e[i] * rinv;
}

// ---------------------------------------------------------------------------
// ctxbar[b,i] = sum_s alpha[b,s] * context[b,s,i]   (fp32 streaming reduction)
// grid (8 i-chunks of 64, B).  hidden = Wc@ctxbar + bc follows via rowgemm.
// ---------------------------------------------------------------------------
__global__ void ctxbar_kernel(const float* __restrict__ context,
                              const float* __restrict__ alpha,
                              float* __restrict__ ctxbar)
{
  __shared__ float4 red[16][16];
  __shared__ float asm_[S_];
  const int b = blockIdx.y, i0 = blockIdx.x * 64;
  const int t = threadIdx.x, i4 = t & 15, sg = t >> 4;

  const float* ap = alpha + (size_t)b * S_;
  for (int i = t; i < S_; i += 256) asm_[i] = ap[i];
  __syncthreads();

  const float* src = context + (size_t)b * S_ * INP_ + i0 + i4 * 4;
  float4 acc = {0.f, 0.f, 0.f, 0.f};
  #pragma unroll 4
  for (int s = sg; s < S_; s += 16) {
    float wgt = asm_[s];
    float4 v = *(const float4*)(src + (size_t)s * INP_);
    acc.x += wgt * v.x; acc.y += wgt * v.y;
    acc.z += wgt * v.z; acc.w += wgt * v.w;
  }
  red[sg][i4] = acc;
  __syncthreads();
  #pragma unroll
  for (int off = 8; off >= 1; off >>= 1) {
    if (sg < off) {
      float4 o = red[sg + off][i4];
      acc.x += o.x; acc.y += o.y; acc.z += o.z; acc.w += o.w;
      red[sg][i4] = acc;
    }
    __syncthreads();
  }
  if (sg == 0)
    *(float4*)(ctxbar + (size_t)b * 512 + i0 + i4 * 4) = acc;
}

// ---------------------------------------------------------------------------
extern "C" void kernel_launch(void* const* d_in, const int* in_sizes, int n_in,
                              void* d_out, int out_size, void* d_ws, size_t ws_size,
                              hipStream_t stream)
{
  const float* inp     = (const float*)d_in[0];
  const float* context = (const float*)d_in[1];
  const void*  mask    = d_in[2];
  const float* Wl      = (const float*)d_in[3];
  const float* bl      = (const float*)d_in[4];
  const float* Wc      = (const float*)d_in[5];
  const float* bc      = (const float*)d_in[6];
  const float* V       = (const float*)d_in[7];

  float* hidden = (float*)d_out;                 // [B, HID]
  float* alpha  = (float*)d_out + B_ * HID_;     // [B, S]

  char* ws = (char*)d_ws;
  float* hid_ws          = (float*)ws;                            // 128 KB
  float* att_ws          = (float*)(ws + (128 << 10));            // 512 KB
  float* ctxbar_ws       = (float*)(ws + (640 << 10));            // 128 KB
  unsigned short* pk     = (unsigned short*)(ws + (768 << 10));   // 512 KB

  rowgemm_kernel<<<dim3(HID_ / 4, B_), 256, 0, stream>>>(inp, Wl, bl, hid_ws);
  pack_wc_kernel<<<128, 256, 0, stream>>>(Wc, pk);
  ctx_gemm_kernel<<<dim3(S_ / 64, B_), 256, 0, stream>>>(context, pk, hid_ws, bc, V, att_ws);
  softmax_kernel<<<B_, 256, 0, stream>>>(mask, att_ws, alpha);
  ctxbar_kernel<<<dim3(8, B_), 256, 0, stream>>>(context, alpha, ctxbar_ws);
  rowgemm_kernel<<<dim3(HID_ / 4, B_), 256, 0, stream>>>(ctxbar_ws, Wc, bc, hidden);
}

// Round 3
// 532.031 us; speedup vs baseline: 1.2019x; 1.2019x over previous
//
#include <hip/hip_runtime.h>
#include <hip/hip_bf16.h>
#include <cstdint>
#include <cstddef>

#define B_   64
#define S_   2048
#define INP_ 512
#define HID_ 512

typedef float          floatx4  __attribute__((ext_vector_type(4)));
typedef __bf16         bf16x8   __attribute__((ext_vector_type(8)));
typedef unsigned short ushortx8 __attribute__((ext_vector_type(8)));
typedef unsigned short ushortx4 __attribute__((ext_vector_type(4)));

__device__ __forceinline__ unsigned short f2bf(float f) {
  unsigned u = __float_as_uint(f);
  u += 0x7FFFu + ((u >> 16) & 1u);          // round-to-nearest-even
  return (unsigned short)(u >> 16);
}
// tanh(x) = 1 - 2/(exp(2x)+1); inf-safe at both tails.
__device__ __forceinline__ float fast_tanh(float x) {
  float u = __builtin_amdgcn_exp2f(x * 2.88539008177792681472f);
  return 1.0f - 2.0f * __builtin_amdgcn_rcpf(u + 1.0f);
}

// ---------------------------------------------------------------------------
// rowgemm: out[b,h] = bias[h] + dot(W[h,:], X[b,:])   (one wave per h)
// ---------------------------------------------------------------------------
__global__ void rowgemm_kernel(const float* __restrict__ X, const float* __restrict__ W,
                               const float* __restrict__ bias, float* __restrict__ out)
{
  const int b = blockIdx.y;
  const int w = threadIdx.x >> 6, lane = threadIdx.x & 63;
  const int h = blockIdx.x * 4 + w;
  const float4* wr = (const float4*)(W + (size_t)h * 512) + lane * 2;
  const float4* xr = (const float4*)(X + (size_t)b * 512) + lane * 2;
  float4 w0 = wr[0], w1 = wr[1], x0 = xr[0], x1 = xr[1];
  float acc = w0.x*x0.x + w0.y*x0.y + w0.z*x0.z + w0.w*x0.w
            + w1.x*x1.x + w1.y*x1.y + w1.z*x1.z + w1.w*x1.w;
  #pragma unroll
  for (int off = 32; off; off >>= 1) acc += __shfl_xor(acc, off);
  if (lane == 0) out[b * 512 + h] = bias[h] + acc;
}

// ---------------------------------------------------------------------------
// pack Wc (fp32 [HID][INP]) -> bf16 in MFMA A-fragment lane order.
// pk[(m16*1024 + ks*64 + lane)*8 + j] = Wc[m16*16 + (lane&15)][ks*32 + (lane>>4)*8 + j]
// ---------------------------------------------------------------------------
__global__ void pack_wc_kernel(const float* __restrict__ Wc, unsigned short* __restrict__ pk)
{
  int g = blockIdx.x * 256 + threadIdx.x;       // 32768 threads
  int l = g & 63, ks = (g >> 6) & 15, m16 = g >> 10;
  int row = m16 * 16 + (l & 15);
  int kb  = ks * 32 + (l >> 4) * 8;
  const float4* s = (const float4*)(Wc + (size_t)row * 512 + kb);
  float4 a = s[0], c = s[1];
  ushortx8 o = { f2bf(a.x), f2bf(a.y), f2bf(a.z), f2bf(a.w),
                 f2bf(c.x), f2bf(c.y), f2bf(c.z), f2bf(c.w) };
  *(ushortx8*)(pk + (size_t)g * 8) = o;
}

// ---------------------------------------------------------------------------
// ctx_gemm: att[b,s] = sum_h V[h]*tanh(hid[b,h] + bc[h] + sum_k Wc[h,k]*context[b,s,k])
// Full-H per block, 64-s tile.  Pipeline per K-phase (128 floats):
//   DMA (global_load_lds, fp32, async, 0 regs) phase p+1 -> fbuf
//   MFMA compute on bf16 tile (phase p)            <- overlapped with DMA
//   barrier; convert fbuf -> bf16 tile; barrier
// Source-side DMA swizzle makes convert-pass LDS accesses linear and keeps
// the bf16 tile in R1's verified swizzled layout (B-frag chunk c at slot
// c^(row&7)).  Inner loop identical to R1 (no conversion -> no spills).
// ---------------------------------------------------------------------------
__global__ __launch_bounds__(256, 2) void ctx_gemm_kernel(
    const float* __restrict__ context, const unsigned short* __restrict__ Wc_pk,
    const float* __restrict__ hid, const float* __restrict__ bc,
    const float* __restrict__ V, float* __restrict__ att)
{
  __shared__ alignas(16) float          fbuf[64 * 128];   // 32 KB fp32 DMA target
  __shared__ alignas(16) unsigned short bsm[64 * 128];    // 16 KB bf16 compute tile

  const int b    = blockIdx.y;
  const int s0   = blockIdx.x * 64;
  const int t    = threadIdx.x;
  const int lane = t & 63;
  const int w    = t >> 6;           // wave id: h-rows [w*128, w*128+128)
  const int quad = lane >> 4;
  const int l15  = lane & 15;

  floatx4 acc[8][4];
  #pragma unroll
  for (int m = 0; m < 8; ++m)
    #pragma unroll
    for (int n = 0; n < 4; ++n) { floatx4 z = {0.f,0.f,0.f,0.f}; acc[m][n] = z; }

  const unsigned short* apBase = Wc_pk + (size_t)(w * 8) * 8192 + lane * 8;
  const float* src = context + ((size_t)b * S_ + s0) * INP_;
  auto* gsrc = (const __attribute__((address_space(1))) float*)src;
  auto* fdst = (__attribute__((address_space(3))) float*)fbuf;

  // DMA one K-phase (64 rows x 128 floats).  LDS dest is lane-linear (m104);
  // swizzle lives in the SOURCE granule index: fbuf slot cl of row holds
  // global float4-granule cg = ((cl>>1)^(row&7))*2 | (cl&1).
  auto dma = [&](int phase) {
    #pragma unroll
    for (int i = 0; i < 8; ++i) {
      int id  = t + i * 256;               // 0..2047 float4-granules
      int row = id >> 5;
      int cl  = id & 31;
      int cg  = (((cl >> 1) ^ (row & 7)) << 1) | (cl & 1);
      __builtin_amdgcn_global_load_lds(
          (const __attribute__((address_space(1))) void*)(gsrc + (size_t)row * INP_ + phase * 128 + cg * 4),
          (__attribute__((address_space(3))) void*)(fdst + id * 4), 16, 0, 0);
    }
  };
  // Convert fbuf -> bsm.  Both sides linear in id => conflict-free; the
  // source swizzle lands granule cg exactly at bf16 slot (cg>>1)^(row&7).
  auto convert = [&]() {
    #pragma unroll
    for (int i = 0; i < 8; ++i) {
      int id = t + i * 256;
      float4 v = *(const float4*)(fbuf + id * 4);
      ushortx4 o = { f2bf(v.x), f2bf(v.y), f2bf(v.z), f2bf(v.w) };
      *(ushortx4*)(&bsm[id * 4]) = o;
    }
  };

  dma(0);
  __syncthreads();                         // vmcnt(0) drain: DMA(0) in LDS
  convert();
  __syncthreads();

  for (int phase = 0; phase < 4; ++phase) {
    if (phase < 3) dma(phase + 1);         // async, in flight through compute
    #pragma unroll
    for (int ksl = 0; ksl < 4; ++ksl) {
      const int ksg = phase * 4 + ksl;
      bf16x8 af[8];
      #pragma unroll
      for (int m = 0; m < 8; ++m)
        af[m] = *(const bf16x8*)(apBase + (size_t)m * 8192 + ksg * 512);
      bf16x8 bfr[4];
      #pragma unroll
      for (int n = 0; n < 4; ++n) {
        const int row = n * 16 + l15;
        const int c   = ksl * 4 + quad;
        bfr[n] = *(const bf16x8*)(&bsm[row * 128 + ((c ^ (row & 7)) * 8)]);
      }
      #pragma unroll
      for (int m = 0; m < 8; ++m)
        #pragma unroll
        for (int n = 0; n < 4; ++n)
          acc[m][n] = __builtin_amdgcn_mfma_f32_16x16x32_bf16(af[m], bfr[n], acc[m][n], 0, 0, 0);
    }
    __syncthreads();                       // all waves done reading bsm + DMA drained
    if (phase < 3) {
      convert();
      __syncthreads();
    }
  }

  // Epilogue: att reduction over h.  C/D layout: col(s)=lane&15, row(h)=quad*4+reg.
  float* attsm = fbuf;                     // fbuf dead after last convert
  if (t < 64) attsm[t] = 0.0f;
  __syncthreads();

  float attacc[4] = {0.f, 0.f, 0.f, 0.f};
  #pragma unroll
  for (int m = 0; m < 8; ++m) {
    const int hb = w * 128 + m * 16 + quad * 4;
    #pragma unroll
    for (int r = 0; r < 4; ++r) {
      const int h = hb + r;
      const float bcv = bc[h], hv = hid[b * 512 + h], vv = V[h];
      #pragma unroll
      for (int n = 0; n < 4; ++n)
        attacc[n] += vv * fast_tanh(hv + bcv + acc[m][n][r]);
    }
  }
  #pragma unroll
  for (int n = 0; n < 4; ++n) {
    float v = attacc[n];
    v += __shfl_xor(v, 16);
    v += __shfl_xor(v, 32);
    if (lane < 16) atomicAdd(&attsm[n * 16 + l15], v);
  }
  __syncthreads();
  if (t < 64) att[b * S_ + s0 + t] = attsm[t];
}

// ---------------------------------------------------------------------------
// masked softmax over S per batch row (mask-encoding auto-detect).
// ---------------------------------------------------------------------------
__global__ void softmax_kernel(const void* __restrict__ mask,
                               const float* __restrict__ att,
                               float* __restrict__ alpha)
{
  __shared__ int flags;
  __shared__ float red[8];
  const int b = blockIdx.x, t = threadIdx.x;
  const int lane = t & 63, w = t >> 6;
  if (t == 0) flags = 0;
  __syncthreads();
  int f = 0;
  const unsigned* mw = (const unsigned*)mask;
  for (int i = t; i < 512; i += 256) {
    unsigned v = mw[i];
    if (v > 1u) f |= 1;
    if (v != 0u && v != 0x3f800000u) f |= 2;
  }
  if (f) atomicOr(&flags, f);
  __syncthreads();
  const int fl = flags;
  const int mode = ((fl & 1) == 0) ? 0 : (((fl & 2) == 0) ? 1 : 2);

  float v[8]; bool msk[8];
  float vmax = -1e30f;
  #pragma unroll
  for (int i = 0; i < 8; ++i) {
    int idx = i * 256 + t;
    bool m;
    if (mode == 0)      m = ((const int*)mask)[b * S_ + idx] != 0;
    else if (mode == 1) m = ((const float*)mask)[b * S_ + idx] != 0.0f;
    else                m = ((const unsigned char*)mask)[b * S_ + idx] != 0;
    msk[i] = m;
    v[i] = att[b * S_ + idx];
    if (!m) vmax = fmaxf(vmax, v[i]);
  }
  #pragma unroll
  for (int off = 32; off; off >>= 1) vmax = fmaxf(vmax, __shfl_xor(vmax, off));
  if (lane == 0) red[w] = vmax;
  __syncthreads();
  vmax = fmaxf(fmaxf(red[0], red[1]), fmaxf(red[2], red[3]));

  float e[8], s = 0.0f;
  #pragma unroll
  for (int i = 0; i < 8; ++i) {
    e[i] = msk[i] ? 0.0f : __builtin_amdgcn_exp2f((v[i] - vmax) * 1.4426950408889634f);
    s += e[i];
  }
  #pragma unroll
  for (int off = 32; off; off >>= 1) s += __shfl_xor(s, off);
  if (lane == 0) red[4 + w] = s;
  __syncthreads();
  s = red[4] + red[5] + red[6] + red[7];
  float rinv = 1.0f / s;
  #pragma unroll
  for (int i = 0; i < 8; ++i)
    alpha[b * S_ + i * 256 + t] = e[i] * rinv;
}

// ---------------------------------------------------------------------------
// ctxbar[b,i] += sum_s alpha[b,s]*context[b,s,i], block = (s-chunk of 256, b).
// Fully sequential 512 KB stream per block, 16 B/lane coalesced; fp32
// atomicAdd epilogue (ctxbar zeroed via hipMemsetAsync).
// ---------------------------------------------------------------------------
__global__ void ctxbar_kernel(const float* __restrict__ context,
                              const float* __restrict__ alpha,
                              float* __restrict__ ctxbar)
{
  __shared__ float asm_[256];
  const int b = blockIdx.y, s0 = blockIdx.x * 256, t = threadIdx.x;
  const int half = t >> 7, tt = t & 127;   // threads 0..127: even rows; 128..255: odd
  asm_[t] = alpha[(size_t)b * S_ + s0 + t];
  __syncthreads();
  const float* src = context + ((size_t)b * S_ + s0) * INP_ + tt * 4;
  float4 acc = {0.f, 0.f, 0.f, 0.f};
  #pragma unroll 4
  for (int r = half; r < 256; r += 2) {
    float wv = asm_[r];
    float4 v = *(const float4*)(src + (size_t)r * INP_);
    acc.x += wv * v.x; acc.y += wv * v.y;
    acc.z += wv * v.z; acc.w += wv * v.w;
  }
  float* dst = ctxbar + b * 512 + tt * 4;
  atomicAdd(dst + 0, acc.x);
  atomicAdd(dst + 1, acc.y);
  atomicAdd(dst + 2, acc.z);
  atomicAdd(dst + 3, acc.w);
}

// ---------------------------------------------------------------------------
extern "C" void kernel_launch(void* const* d_in, const int* in_sizes, int n_in,
                              void* d_out, int out_size, void* d_ws, size_t ws_size,
                              hipStream_t stream)
{
  const float* inp     = (const float*)d_in[0];
  const float* context = (const float*)d_in[1];
  const void*  mask    = d_in[2];
  const float* Wl      = (const float*)d_in[3];
  const float* bl      = (const float*)d_in[4];
  const float* Wc      = (const float*)d_in[5];
  const float* bc      = (const float*)d_in[6];
  const float* V       = (const float*)d_in[7];

  float* hidden = (float*)d_out;                 // [B, HID]
  float* alpha  = (float*)d_out + B_ * HID_;     // [B, S]

  char* ws = (char*)d_ws;
  float* hid_ws          = (float*)ws;                            // 128 KB
  float* att_ws          = (float*)(ws + (128 << 10));            // 512 KB
  float* ctxbar_ws       = (float*)(ws + (640 << 10));            // 128 KB
  unsigned short* pk     = (unsigned short*)(ws + (768 << 10));   // 512 KB

  hipMemsetAsync(ctxbar_ws, 0, B_ * HID_ * sizeof(float), stream);
  rowgemm_kernel<<<dim3(HID_ / 4, B_), 256, 0, stream>>>(inp, Wl, bl, hid_ws);
  pack_wc_kernel<<<128, 256, 0, stream>>>(Wc, pk);
  ctx_gemm_kernel<<<dim3(S_ / 64, B_), 256, 0, stream>>>(context, pk, hid_ws, bc, V, att_ws);
  softmax_kernel<<<B_, 256, 0, stream>>>(mask, att_ws, alpha);
  ctxbar_kernel<<<dim3(S_ / 256, B_), 256, 0, stream>>>(context, alpha, ctxbar_ws);
  rowgemm_kernel<<<dim3(HID_ / 4, B_), 256, 0, stream>>>(ctxbar_ws, Wc, bc, hidden);
}

// Round 4
// 528.220 us; speedup vs baseline: 1.2106x; 1.0072x over previous
//
#include <hip/hip_runtime.h>
#include <hip/hip_bf16.h>
#include <cstdint>
#include <cstddef>

#define B_   64
#define S_   2048
#define INP_ 512
#define HID_ 512
#define LOG2E 1.4426950408889634f

typedef float          floatx4  __attribute__((ext_vector_type(4)));
typedef __bf16         bf16x8   __attribute__((ext_vector_type(8)));
typedef unsigned short ushortx8 __attribute__((ext_vector_type(8)));

__device__ __forceinline__ unsigned short f2bf(float f) {
  unsigned u = __float_as_uint(f);
  u += 0x7FFFu + ((u >> 16) & 1u);          // round-to-nearest-even
  return (unsigned short)(u >> 16);
}
__device__ __forceinline__ float bf2f(unsigned short h) {
  return __uint_as_float(((unsigned)h) << 16);
}
// tanh(x) = 1 - 2/(exp(2x)+1); inf-safe at both tails.
__device__ __forceinline__ float fast_tanh(float x) {
  float u = __builtin_amdgcn_exp2f(x * 2.88539008177792681472f);
  return 1.0f - 2.0f * __builtin_amdgcn_rcpf(u + 1.0f);
}

// ---------------------------------------------------------------------------
// prep: blocks [0,64): hid[b,:] = inp[b]@Wl.T + bl
//       blocks [64,192): pack Wc -> bf16 MFMA A-fragment order
//       blocks [192,256): canonicalize mask -> byte mask (encoding auto-detect)
// ---------------------------------------------------------------------------
__global__ void prep_kernel(const float* __restrict__ inp, const float* __restrict__ Wl,
                            const float* __restrict__ bl, const float* __restrict__ Wc,
                            const void* __restrict__ mask,
                            float* __restrict__ hid, unsigned short* __restrict__ pk,
                            unsigned char* __restrict__ maskb)
{
  const int blk = blockIdx.x, t = threadIdx.x;
  if (blk < 64) {                                   // ---- hid ----
    __shared__ float ism[512];
    const int b = blk;
    ism[t]       = inp[b * 512 + t];
    ism[t + 256] = inp[b * 512 + 256 + t];
    __syncthreads();
    #pragma unroll
    for (int hh = 0; hh < 2; ++hh) {
      int h = t + hh * 256;
      const float4* wr = (const float4*)(Wl + (size_t)h * 512);
      float4 sv = {0.f, 0.f, 0.f, 0.f};
      for (int i = 0; i < 128; ++i) {
        float4 wv = wr[i];
        float4 iv = *(const float4*)(&ism[i * 4]);
        sv.x += wv.x * iv.x; sv.y += wv.y * iv.y;
        sv.z += wv.z * iv.z; sv.w += wv.w * iv.w;
      }
      hid[b * 512 + h] = bl[h] + sv.x + sv.y + sv.z + sv.w;
    }
  } else if (blk < 192) {                           // ---- pack Wc ----
    int g = (blk - 64) * 256 + t;                   // 32768 total
    int l = g & 63, ks = (g >> 6) & 15, m16 = g >> 10;
    int row = m16 * 16 + (l & 15);
    int kb  = ks * 32 + (l >> 4) * 8;
    const float4* s = (const float4*)(Wc + (size_t)row * 512 + kb);
    float4 a = s[0], c = s[1];
    ushortx8 o = { f2bf(a.x), f2bf(a.y), f2bf(a.z), f2bf(a.w),
                   f2bf(c.x), f2bf(c.y), f2bf(c.z), f2bf(c.w) };
    *(ushortx8*)(pk + (size_t)g * 8) = o;
  } else {                                          // ---- mask canonicalize ----
    __shared__ int flags;
    const int b = blk - 192;
    if (t == 0) flags = 0;
    __syncthreads();
    int f = 0;
    const unsigned* mw = (const unsigned*)mask;
    for (int i = t; i < 512; i += 256) {
      unsigned v = mw[i];
      if (v > 1u) f |= 1;                           // not int32 0/1
      if (v != 0u && v != 0x3f800000u) f |= 2;      // not float32 0.0/1.0
    }
    if (f) atomicOr(&flags, f);
    __syncthreads();
    const int fl = flags;
    const int mode = ((fl & 1) == 0) ? 0 : (((fl & 2) == 0) ? 1 : 2);
    #pragma unroll
    for (int k = 0; k < 8; ++k) {
      int idx = k * 256 + t;
      bool m;
      if (mode == 0)      m = ((const int*)mask)[b * S_ + idx] != 0;
      else if (mode == 1) m = ((const float*)mask)[b * S_ + idx] != 0.0f;
      else                m = ((const unsigned char*)mask)[b * S_ + idx] != 0;
      maskb[b * S_ + idx] = m ? 1 : 0;
    }
  }
}

// ---------------------------------------------------------------------------
// ctx_gemm: per (b, 64-s tile):
//   D[h,s] = sum_k Wc[h,k]*context[b,s,k]          (bf16 MFMA, full H=512)
//   att[s] = sum_h V[h]*tanh(hid[h]+bc[h]+D[h,s])  (global atomicAdd reduce)
//   p_s = exp(att_s - m_loc) (masked: 0), l_loc = sum p
//   partial[i] = sum_s p_s * c_bf16[s,i]           (context tile still in LDS!)
// Single context pass for the whole problem.  512 thr / 8 waves, M=64/wave.
// bsm = full-K 64x512 bf16 (64 KB), built in 8 K64 stages, VGPR-staged loads.
// Swizzle: granule g of row r stored at slot (g&~7)|((g^r)&7).
// ---------------------------------------------------------------------------
__global__ __launch_bounds__(512, 2) void ctx_gemm_kernel(
    const float* __restrict__ context, const unsigned short* __restrict__ Wc_pk,
    const float* __restrict__ hid, const float* __restrict__ bc,
    const float* __restrict__ V, const unsigned char* __restrict__ maskb,
    float* __restrict__ att, float* __restrict__ ml, float* __restrict__ part)
{
  __shared__ alignas(16) unsigned short bsm[64 * 512];   // 64 KB, full-K bf16 tile

  const int b    = blockIdx.y;
  const int tile = blockIdx.x;
  const int s0   = tile * 64;
  const int t    = threadIdx.x;
  const int lane = t & 63;
  const int w    = t >> 6;            // wave id: h in [64w, 64w+64)
  const int quad = lane >> 4;
  const int l15  = lane & 15;
  const int srow = t >> 3;            // staging: s-row 0..63
  const int sgl  = t & 7;             // staging: granule 0..7 within stage

  const float* src = context + ((size_t)b * S_ + s0) * INP_;

  floatx4 acc[4][4];
  #pragma unroll
  for (int m = 0; m < 4; ++m)
    #pragma unroll
    for (int n = 0; n < 4; ++n) { floatx4 z = {0.f,0.f,0.f,0.f}; acc[m][n] = z; }

  float4 f0, f1;                       // staging regs (one 16B granule / thread / stage)
  auto loadst = [&](int s) {
    const float* p = src + (size_t)srow * INP_ + s * 64 + sgl * 8;
    f0 = *(const float4*)p;
    f1 = *(const float4*)(p + 4);
  };
  auto writest = [&](int s) {
    int slot = s * 8 + ((sgl ^ srow) & 7);
    ushortx8 o = { f2bf(f0.x), f2bf(f0.y), f2bf(f0.z), f2bf(f0.w),
                   f2bf(f1.x), f2bf(f1.y), f2bf(f1.z), f2bf(f1.w) };
    *(ushortx8*)(&bsm[srow * 512 + slot * 8]) = o;
  };

  loadst(0);
  writest(0);
  __syncthreads();

  for (int s = 0; s < 8; ++s) {
    if (s < 7) loadst(s + 1);          // global->VGPR, in flight during MFMA
    #pragma unroll
    for (int ksl = 0; ksl < 2; ++ksl) {
      const int ksg = s * 2 + ksl;
      bf16x8 af[4];
      #pragma unroll
      for (int m = 0; m < 4; ++m)
        af[m] = *(const bf16x8*)(Wc_pk + ((size_t)(w * 4 + m) * 1024 + ksg * 64 + lane) * 8);
      bf16x8 bfr[4];
      #pragma unroll
      for (int n = 0; n < 4; ++n) {
        const int row = n * 16 + l15;
        const int g   = ksg * 4 + quad;
        const int slot = (g & ~7) | ((g ^ row) & 7);
        bfr[n] = *(const bf16x8*)(&bsm[row * 512 + slot * 8]);
      }
      #pragma unroll
      for (int m = 0; m < 4; ++m)
        #pragma unroll
        for (int n = 0; n < 4; ++n)
          acc[m][n] = __builtin_amdgcn_mfma_f32_16x16x32_bf16(af[m], bfr[n], acc[m][n], 0, 0, 0);
    }
    if (s < 7) {
      writest(s + 1);                  // region s+1: disjoint from readers of region s
      __syncthreads();
    }
  }

  // ---- att: per-wave partial over its 64 h, then cross-wave via global atomics.
  // C/D layout: col(s)=lane&15, row(h)=quad*4+reg.
  float attacc[4] = {0.f, 0.f, 0.f, 0.f};
  #pragma unroll
  for (int m = 0; m < 4; ++m) {
    #pragma unroll
    for (int r = 0; r < 4; ++r) {
      const int h = w * 64 + m * 16 + quad * 4 + r;
      const float s3 = hid[b * 512 + h] + bc[h];
      const float vv = V[h];
      #pragma unroll
      for (int n = 0; n < 4; ++n)
        attacc[n] += vv * fast_tanh(s3 + acc[m][n][r]);
    }
  }
  float* attRow = att + (size_t)b * S_ + s0;
  #pragma unroll
  for (int n = 0; n < 4; ++n) {
    float v = attacc[n];
    v += __shfl_xor(v, 16);
    v += __shfl_xor(v, 32);
    if (lane < 16) atomicAdd(&attRow[n * 16 + l15], v);
  }
  __syncthreads();                     // drains vmcnt incl. atomics -> L2 complete

  // ---- per-lane: s = lane.  Atomic readback bypasses (possibly stale) L1.
  float am = atomicAdd(&attRow[lane], 0.0f);
  if (maskb[(size_t)b * S_ + s0 + lane]) am = -1e30f;
  float mloc = am;
  #pragma unroll
  for (int off = 32; off; off >>= 1) mloc = fmaxf(mloc, __shfl_xor(mloc, off));
  float p = __builtin_amdgcn_exp2f((am - mloc) * LOG2E);
  float lloc = p;
  #pragma unroll
  for (int off = 32; off; off >>= 1) lloc += __shfl_xor(lloc, off);
  if (t == 0) {
    ml[((size_t)b * 32 + tile) * 2 + 0] = mloc;
    ml[((size_t)b * 32 + tile) * 2 + 1] = lloc;
  }

  // ---- partial[i] = sum_s p_s * c_bf16[s,i]; thread t owns i=t.
  const int gi = t >> 3, ie = t & 7;
  float pacc = 0.0f;
  #pragma unroll 8
  for (int j = 0; j < 64; ++j) {
    float pj = __shfl(p, j);
    const int slot = (gi & ~7) | ((gi ^ j) & 7);
    pacc += pj * bf2f(bsm[j * 512 + slot * 8 + ie]);
  }
  part[((size_t)b * 32 + tile) * 512 + t] = pacc;
}

// ---------------------------------------------------------------------------
// combine (one block per b): merge 32 tile-partials (online-softmax rescale),
// emit alpha and hidden = Wc@ctxbar + bc.
// ---------------------------------------------------------------------------
__global__ void combine_kernel(const float* __restrict__ att, const float* __restrict__ ml,
                               const float* __restrict__ part, const unsigned char* __restrict__ maskb,
                               const float* __restrict__ Wc, const float* __restrict__ bc,
                               float* __restrict__ hidden, float* __restrict__ alpha)
{
  __shared__ float msm[32], lsm[32], wsm[32];
  __shared__ float cbar[512];
  const int b = blockIdx.x, t = threadIdx.x;

  if (t < 32) {
    msm[t] = ml[((size_t)b * 32 + t) * 2 + 0];
    lsm[t] = ml[((size_t)b * 32 + t) * 2 + 1];
  }
  __syncthreads();
  float mg = -1e30f;
  #pragma unroll
  for (int i = 0; i < 32; ++i) mg = fmaxf(mg, msm[i]);
  float lg = 0.0f;
  #pragma unroll
  for (int i = 0; i < 32; ++i) lg += __builtin_amdgcn_exp2f((msm[i] - mg) * LOG2E) * lsm[i];
  if (t < 32) wsm[t] = __builtin_amdgcn_exp2f((msm[t] - mg) * LOG2E);
  const float rinv = 1.0f / lg;
  __syncthreads();

  // ctxbar[i] = (sum_tile w_tile * part[tile][i]) / lg
  #pragma unroll
  for (int ii = 0; ii < 2; ++ii) {
    const int i = t + ii * 256;
    float a = 0.0f;
    #pragma unroll 8
    for (int j = 0; j < 32; ++j)
      a += wsm[j] * part[((size_t)b * 32 + j) * 512 + i];
    cbar[i] = a * rinv;
  }
  // alpha
  #pragma unroll
  for (int k = 0; k < 8; ++k) {
    const int s = k * 256 + t;
    float a = maskb[(size_t)b * S_ + s] ? 0.0f
            : __builtin_amdgcn_exp2f((att[(size_t)b * S_ + s] - mg) * LOG2E) * rinv;
    alpha[(size_t)b * S_ + s] = a;
  }
  __syncthreads();
  // hidden[h] = bc[h] + Wc[h,:]·cbar
  #pragma unroll
  for (int hh = 0; hh < 2; ++hh) {
    const int h = t + hh * 256;
    const float4* wr = (const float4*)(Wc + (size_t)h * 512);
    const float4* cb = (const float4*)cbar;
    float4 sv = {0.f, 0.f, 0.f, 0.f};
    for (int i = 0; i < 128; ++i) {
      float4 wv = wr[i];
      float4 cv = cb[i];
      sv.x += wv.x * cv.x; sv.y += wv.y * cv.y;
      sv.z += wv.z * cv.z; sv.w += wv.w * cv.w;
    }
    hidden[b * 512 + h] = bc[h] + sv.x + sv.y + sv.z + sv.w;
  }
}

// ---------------------------------------------------------------------------
extern "C" void kernel_launch(void* const* d_in, const int* in_sizes, int n_in,
                              void* d_out, int out_size, void* d_ws, size_t ws_size,
                              hipStream_t stream)
{
  const float* inp     = (const float*)d_in[0];
  const float* context = (const float*)d_in[1];
  const void*  mask    = d_in[2];
  const float* Wl      = (const float*)d_in[3];
  const float* bl      = (const float*)d_in[4];
  const float* Wc      = (const float*)d_in[5];
  const float* bc      = (const float*)d_in[6];
  const float* V       = (const float*)d_in[7];

  float* hidden = (float*)d_out;                 // [B, HID]
  float* alpha  = (float*)d_out + B_ * HID_;     // [B, S]

  char* ws = (char*)d_ws;
  float*          hid_ws = (float*)ws;                             // 128 KB
  unsigned short* pk     = (unsigned short*)(ws + (128 << 10));    // 512 KB
  unsigned char*  maskb  = (unsigned char*)(ws + (640 << 10));     // 128 KB
  float*          att_ws = (float*)(ws + (768 << 10));             // 512 KB
  float*          ml_ws  = (float*)(ws + (1280 << 10));            // 16 KB
  float*          part_ws= (float*)(ws + (1296 << 10));            // 4 MB
  // total ~5.3 MB

  hipMemsetAsync(att_ws, 0, (size_t)B_ * S_ * sizeof(float), stream);
  prep_kernel<<<256, 256, 0, stream>>>(inp, Wl, bl, Wc, mask, hid_ws, pk, maskb);
  ctx_gemm_kernel<<<dim3(S_ / 64, B_), 512, 0, stream>>>(
      context, pk, hid_ws, bc, V, maskb, att_ws, ml_ws, part_ws);
  combine_kernel<<<B_, 256, 0, stream>>>(att_ws, ml_ws, part_ws, maskb, Wc, bc, hidden, alpha);
}